// Round 1
// baseline (289.053 us; speedup 1.0000x reference)
//
#include <hip/hip_runtime.h>

#define B_ 128
#define T_ 64
#define N_ 197
#define D_ 768

__device__ __forceinline__ float waveSum(float v){
#pragma unroll
  for (int m = 32; m >= 1; m >>= 1) v += __shfl_xor(v, m, 64);
  return v;
}

// monotone map float -> uint32 so integer compare == float compare
__device__ __forceinline__ unsigned ordf(float x){
  unsigned u = __float_as_uint(x);
  return (u & 0x80000000u) ? ~u : (u | 0x80000000u);
}

// ---------------- Kernel 1: target invnorm + image MSE partials + cls partials
__global__ __launch_bounds__(192) void k_norm_img(
    const float* __restrict__ image, const float* __restrict__ text,
    const float* __restrict__ target, float* __restrict__ invnorm,
    float* __restrict__ img_partial, float* __restrict__ cls_partial){
  int row = blockIdx.x;            // b*N_ + n
  int b = row / N_;
  int n = row - b * N_;
  int i = threadIdx.x;             // 0..191, 4 floats each = 768
  const float4* tg4 = reinterpret_cast<const float4*>(target + (size_t)row * D_);
  const float4* im4 = reinterpret_cast<const float4*>(image + (size_t)row * D_);
  float4 t4 = tg4[i];
  float4 g4 = im4[i];
  float ss = t4.x*t4.x + t4.y*t4.y + t4.z*t4.z + t4.w*t4.w;
  float dx = g4.x-t4.x, dy = g4.y-t4.y, dz = g4.z-t4.z, dw = g4.w-t4.w;
  float sd = dx*dx + dy*dy + dz*dz + dw*dw;
  ss = waveSum(ss); sd = waveSum(sd);
  __shared__ float shs[3], shd[3], shc[3];
  int lane = i & 63, wid = i >> 6;
  if (lane == 0){ shs[wid] = ss; shd[wid] = sd; }
  __syncthreads();
  if (i == 0){
    invnorm[row] = 1.0f / sqrtf(shs[0]+shs[1]+shs[2]);
    img_partial[row] = shd[0]+shd[1]+shd[2];
  }
  if (n == 0){  // block-uniform branch: cls term (text[b,0] - image[b,0])^2
    const float4* tx4 = reinterpret_cast<const float4*>(text + (size_t)b * T_ * D_);
    float4 c4 = tx4[i];
    float cx = c4.x-g4.x, cy = c4.y-g4.y, cz = c4.z-g4.z, cw = c4.w-g4.w;
    float sc = cx*cx + cy*cy + cz*cz + cw*cw;
    sc = waveSum(sc);
    if (lane == 0) shc[wid] = sc;
    __syncthreads();
    if (i == 0) cls_partial[b] = shc[0]+shc[1]+shc[2];
  }
}

// ---------------- Kernel 2: similarity GEMM tile + argmax via packed atomicMax
// grid (4, B_): blockIdx.x = quarter of n-range (49 each), blockIdx.y = batch
__global__ __launch_bounds__(256) void k_sim(
    const float* __restrict__ text, const float* __restrict__ target,
    const float* __restrict__ invnorm, unsigned long long* __restrict__ best){
  int h = blockIdx.x;              // 0..3
  int b = blockIdx.y;
  int n0 = 1 + 49*h;               // n range [n0, n0+49)
  __shared__ float As[16][64];     // [k][t_local], t_local = t-1 (0..62), slot 63 zero
  __shared__ float Bs[16][52];     // [k][nn], nn = n - n0 (0..48)
  int tid = threadIdx.x;
  int tx = tid & 15, ty = tid >> 4;
  int tt = tid & 63, ki = tid >> 6;
  float acc[4][4] = {{0.f,0.f,0.f,0.f},{0.f,0.f,0.f,0.f},{0.f,0.f,0.f,0.f},{0.f,0.f,0.f,0.f}};
  const float* textb = text + (size_t)b * T_ * D_;
  const float* tgtb  = target + (size_t)b * N_ * D_;

  for (int k0 = 0; k0 < D_; k0 += 16){
    // stage A: 64 t-slots x 16 k, one float4 per thread
    float4 av = make_float4(0.f,0.f,0.f,0.f);
    if (tt < 63) av = *reinterpret_cast<const float4*>(textb + (size_t)(1+tt)*D_ + k0 + ki*4);
    As[ki*4+0][tt] = av.x; As[ki*4+1][tt] = av.y; As[ki*4+2][tt] = av.z; As[ki*4+3][tt] = av.w;
    // stage B: 49 n-rows x 16 k = 196 float4
    if (tid < 196){
      int nn = tid >> 2, kj = tid & 3;
      float4 bv = *reinterpret_cast<const float4*>(tgtb + (size_t)(n0+nn)*D_ + k0 + kj*4);
      Bs[kj*4+0][nn] = bv.x; Bs[kj*4+1][nn] = bv.y; Bs[kj*4+2][nn] = bv.z; Bs[kj*4+3][nn] = bv.w;
    }
    __syncthreads();
    if (tx < 13){
#pragma unroll
      for (int k = 0; k < 16; ++k){
        float4 a4 = *reinterpret_cast<const float4*>(&As[k][ty*4]);
        float4 b4 = *reinterpret_cast<const float4*>(&Bs[k][tx*4]);
        float aa[4] = {a4.x, a4.y, a4.z, a4.w};
        float bb[4] = {b4.x, b4.y, b4.z, b4.w};
#pragma unroll
        for (int ii = 0; ii < 4; ++ii)
#pragma unroll
          for (int jj = 0; jj < 4; ++jj)
            acc[ii][jj] = fmaf(aa[ii], bb[jj], acc[ii][jj]);
      }
    }
    __syncthreads();
  }

  // epilogue: scale by target invnorm, per-row argmax, reduce across 16 lanes
  float inv[4];
  if (tx < 13){
#pragma unroll
    for (int jj = 0; jj < 4; ++jj){
      int nn = tx*4 + jj;
      inv[jj] = (nn < 49) ? invnorm[(size_t)b*N_ + n0 + nn] : 0.f;
    }
  }
#pragma unroll
  for (int ii = 0; ii < 4; ++ii){
    unsigned long long key = 0ull;
    if (tx < 13){
      float bv = 0.f; int bn = -1;
#pragma unroll
      for (int jj = 0; jj < 4; ++jj){
        int nn = tx*4 + jj;
        if (nn < 49){
          float v = acc[ii][jj] * inv[jj];
          if (bn < 0 || v > bv){ bv = v; bn = n0 + nn; }
        }
      }
      if (bn >= 0)
        key = ((unsigned long long)ordf(bv) << 32) | (unsigned long long)(0xFFFFFFFFu - (unsigned)bn);
    }
    // reduce over the 16 lanes that share (ty,ii); all lanes participate
#pragma unroll
    for (int m = 1; m < 16; m <<= 1){
      unsigned lo = (unsigned)key, hi = (unsigned)(key >> 32);
      unsigned olo = __shfl_xor(lo, m, 64);
      unsigned ohi = __shfl_xor(hi, m, 64);
      unsigned long long o = ((unsigned long long)ohi << 32) | olo;
      if (o > key) key = o;
    }
    int t_local = ty*4 + ii;
    if (tx == 0 && t_local < 63)
      atomicMax(&best[(size_t)b*63 + t_local], key);
  }
}

// ---------------- Kernel 3: tok_sq for kept tokens
__global__ __launch_bounds__(192) void k_tok(
    const float* __restrict__ text, const float* __restrict__ target,
    const int* __restrict__ pmask, const unsigned long long* __restrict__ best,
    float* __restrict__ tok){
  int bt = blockIdx.x;             // b*63 + t_local
  int b = bt / 63, t = bt - b*63;  // token index 1+t
  if (pmask[b*T_ + 1 + t] != 0){
    if (threadIdx.x == 0) tok[bt] = 0.f;
    return;
  }
  unsigned long long key = best[bt];
  int n = (int)(0xFFFFFFFFu - (unsigned)(key & 0xFFFFFFFFull));
  int i = threadIdx.x;
  const float4* tx4 = reinterpret_cast<const float4*>(text + ((size_t)b*T_ + 1 + t) * D_);
  const float4* tg4 = reinterpret_cast<const float4*>(target + ((size_t)b*N_ + n) * D_);
  float4 a = tx4[i], c = tg4[i];
  float dx = a.x-c.x, dy = a.y-c.y, dz = a.z-c.z, dw = a.w-c.w;
  float sd = dx*dx + dy*dy + dz*dz + dw*dw;
  sd = waveSum(sd);
  __shared__ float sh[3];
  int lane = i & 63, wid = i >> 6;
  if (lane == 0) sh[wid] = sd;
  __syncthreads();
  if (i == 0) tok[bt] = sh[0] + sh[1] + sh[2];
}

// ---------------- Kernel 4: final reduction -> scalar
__global__ __launch_bounds__(256) void k_final(
    const float* __restrict__ img_partial, const float* __restrict__ cls_partial,
    const float* __restrict__ tok, const int* __restrict__ pmask,
    float* __restrict__ out){
  int tid = threadIdx.x;
  float s_img = 0.f, s_cls = 0.f, s_tok = 0.f, s_keep = 0.f;
  for (int i = tid; i < B_*N_; i += 256) s_img += img_partial[i];
  for (int i = tid; i < B_;    i += 256) s_cls += cls_partial[i];
  for (int i = tid; i < B_*63; i += 256){
    s_tok += tok[i];
    int b = i / 63, t = i - b*63;
    s_keep += (pmask[b*T_ + 1 + t] == 0) ? 1.f : 0.f;
  }
  s_img = waveSum(s_img); s_cls = waveSum(s_cls);
  s_tok = waveSum(s_tok); s_keep = waveSum(s_keep);
  __shared__ float sh[4][4];
  int lane = tid & 63, wid = tid >> 6;
  if (lane == 0){ sh[0][wid]=s_img; sh[1][wid]=s_cls; sh[2][wid]=s_tok; sh[3][wid]=s_keep; }
  __syncthreads();
  if (tid == 0){
    float img  = sh[0][0]+sh[0][1]+sh[0][2]+sh[0][3];
    float cls  = sh[1][0]+sh[1][1]+sh[1][2]+sh[1][3];
    float tokm = sh[2][0]+sh[2][1]+sh[2][2]+sh[2][3];
    float keep = sh[3][0]+sh[3][1]+sh[3][2]+sh[3][3];
    float kd_text = (cls + tokm) / ((128.0f + keep) * (float)D_);
    float kd_img  = img / ((float)B_ * (float)N_ * (float)D_);
    out[0] = 0.5f * (kd_text + kd_img);
  }
}

extern "C" void kernel_launch(void* const* d_in, const int* in_sizes, int n_in,
                              void* d_out, int out_size, void* d_ws, size_t ws_size,
                              hipStream_t stream) {
  const float* image  = (const float*)d_in[0];
  const float* text   = (const float*)d_in[1];
  const float* target = (const float*)d_in[2];
  const int*   pmask  = (const int*)d_in[3];

  char* ws = (char*)d_ws;
  // layout: invnorm[25216] f32 | best[8064] u64 | img_partial[25216] f32 | cls_partial[128] f32 | tok[8064] f32
  float* invnorm                 = (float*)(ws);
  unsigned long long* best       = (unsigned long long*)(ws + 100864);
  float* img_partial             = (float*)(ws + 165376);
  float* cls_partial             = (float*)(ws + 266240);
  float* tok                     = (float*)(ws + 266752);

  // zero only the argmax accumulator (packed keys are all > 0 for finite sims)
  hipMemsetAsync(ws + 100864, 0, 64512, stream);

  k_norm_img<<<B_*N_, 192, 0, stream>>>(image, text, target, invnorm, img_partial, cls_partial);
  k_sim<<<dim3(4, B_), 256, 0, stream>>>(text, target, invnorm, best);
  k_tok<<<B_*63, 192, 0, stream>>>(text, target, pmask, best, tok);
  k_final<<<1, 256, 0, stream>>>(img_partial, cls_partial, tok, pmask, (float*)d_out);
}

// Round 10
// 257.423 us; speedup vs baseline: 1.1229x; 1.1229x over previous
//
#include <hip/hip_runtime.h>

#define B_ 128
#define T_ 64
#define N_ 197
#define D_ 768

typedef __attribute__((ext_vector_type(8))) short short8;
typedef __attribute__((ext_vector_type(16))) float f32x16;

__device__ __forceinline__ float waveSum(float v){
#pragma unroll
  for (int m = 32; m >= 1; m >>= 1) v += __shfl_xor(v, m, 64);
  return v;
}
__device__ __forceinline__ unsigned ordf(float x){
  unsigned u = __float_as_uint(x);
  return (u & 0x80000000u) ? ~u : (u | 0x80000000u);
}
__device__ __forceinline__ unsigned short f2bf(float x){
  unsigned u = __float_as_uint(x);
  u += 0x7fffu + ((u >> 16) & 1u);
  return (unsigned short)(u >> 16);
}
__device__ __forceinline__ float bf2f(unsigned s){ return __uint_as_float(s << 16); }

// ================= NEW PATH =================
// Kernel 1: read image/target/text once. Produce: invnorm (target rows),
// bf16 copies of target & text, per-block image-MSE partials, per-batch cls partials.
__global__ __launch_bounds__(256) void k_prep(
    const float* __restrict__ image, const float* __restrict__ text,
    const float* __restrict__ target, float* __restrict__ invnorm,
    unsigned short* __restrict__ tgt_bf, unsigned short* __restrict__ txt_bf,
    float* __restrict__ img_part, float* __restrict__ cls_part){
  int tid = threadIdx.x, lane = tid & 63, wid = tid >> 6;
  int gw = blockIdx.x * 4 + wid;          // 0..8191 (grid must be 2048)
  float img_acc = 0.f;
  for (int row = gw; row < B_*N_; row += 8192){
    int b = row / N_, n = row - b*N_;
    const float4* tg4 = reinterpret_cast<const float4*>(target + (size_t)row*D_);
    const float4* im4 = reinterpret_cast<const float4*>(image + (size_t)row*D_);
    float4 g[3];
    float ss = 0.f, sd = 0.f;
#pragma unroll
    for (int j = 0; j < 3; ++j){
      float4 tv = tg4[j*64 + lane];
      float4 iv = im4[j*64 + lane];
      g[j] = iv;
      ss += tv.x*tv.x + tv.y*tv.y + tv.z*tv.z + tv.w*tv.w;
      float dx = iv.x-tv.x, dy = iv.y-tv.y, dz = iv.z-tv.z, dw = iv.w-tv.w;
      sd += dx*dx + dy*dy + dz*dz + dw*dw;
      uint2 pk;
      pk.x = (unsigned)f2bf(tv.x) | ((unsigned)f2bf(tv.y) << 16);
      pk.y = (unsigned)f2bf(tv.z) | ((unsigned)f2bf(tv.w) << 16);
      *reinterpret_cast<uint2*>(tgt_bf + (size_t)row*D_ + (j*64+lane)*4) = pk;
    }
    ss = waveSum(ss); sd = waveSum(sd);
    img_acc += sd;
    if (lane == 0) invnorm[row] = 1.0f / sqrtf(ss);
    if (n == 0){                           // cls term for batch b
      const float4* tx4 = reinterpret_cast<const float4*>(text + (size_t)b*T_*D_);
      float sc = 0.f;
#pragma unroll
      for (int j = 0; j < 3; ++j){
        float4 cv = tx4[j*64+lane]; float4 iv = g[j];
        float dx = cv.x-iv.x, dy = cv.y-iv.y, dz = cv.z-iv.z, dw = cv.w-iv.w;
        sc += dx*dx + dy*dy + dz*dz + dw*dw;
      }
      sc = waveSum(sc);
      if (lane == 0) cls_part[b] = sc;
    }
  }
  { // text bf16 conversion: exactly one row per wave (8192 rows, 8192 waves)
    int rt = gw;
    const float4* tx4 = reinterpret_cast<const float4*>(text + (size_t)rt*D_);
#pragma unroll
    for (int j = 0; j < 3; ++j){
      float4 v = tx4[j*64+lane];
      uint2 pk;
      pk.x = (unsigned)f2bf(v.x) | ((unsigned)f2bf(v.y) << 16);
      pk.y = (unsigned)f2bf(v.z) | ((unsigned)f2bf(v.w) << 16);
      *reinterpret_cast<uint2*>(txt_bf + (size_t)rt*D_ + (j*64+lane)*4) = pk;
    }
  }
  __shared__ float shp[4];
  if (lane == 0) shp[wid] = img_acc;
  __syncthreads();
  if (tid == 0) img_part[blockIdx.x] = shp[0]+shp[1]+shp[2]+shp[3];
}

// Kernel 2: per-batch MFMA similarity + argmax + fused tok_sq.
// 1 block per batch, 448 threads = 7 waves; wave w owns M-tile w (32 patch rows).
// M = 224 (patches 1..196 + pad), N = 64 cols (col c = token c+1, c<=62 valid), K = 768.
// LDS holds one K-chunk (64) in MFMA-fragment order: frag f at bytes [f*16, f*16+16).
// A frags f = mt*256 + kc*64 + l  (0..1791); B frags 1792 + nt*256 + kc*64 + l.
__global__ __launch_bounds__(448) void k_sim2(
    const unsigned short* __restrict__ txt_bf, const unsigned short* __restrict__ tgt_bf,
    const float* __restrict__ invnorm, const int* __restrict__ pmask,
    float* __restrict__ tok_sum, float* __restrict__ keep_cnt){
  int b = blockIdx.x;
  int tid = threadIdx.x, lane = tid & 63, w = tid >> 6;
  __shared__ char lds[36864];
  __shared__ float invn_s[224];
  __shared__ unsigned long long cand[7][64];
  __shared__ int best_s[64];
  __shared__ float wtok_s[7], wkeep_s[7];

  if (tid < 224) invn_s[tid] = (tid < 196) ? invnorm[b*N_ + 1 + tid] : 0.f;

  // frag ownership: thread handles frags f = tid + s*448, s = 0..5
  const char* tgtb = (const char*)tgt_bf;
  const char* txtb = (const char*)txt_bf;
  const char* fptr[6];
  bool fval[6];
#pragma unroll
  for (int s = 0; s < 6; ++s){
    int f = tid + s*448;
    fval[s] = false; fptr[s] = tgtb;
    if (f < 2304){
      int l = f & 63;
      int kc = (f >> 6) & 3;
      int koff = kc*16 + (l >> 5)*8;
      if (f < 1792){
        int mt = f >> 8;
        int p = 1 + mt*32 + (l & 31);
        if (p <= 196){ fval[s] = true; fptr[s] = tgtb + (((size_t)b*N_ + p)*D_ + koff)*2; }
      } else {
        int nt = (f - 1792) >> 8;
        int c = nt*32 + (l & 31);
        if (c < 63){ fval[s] = true; fptr[s] = txtb + (((size_t)b*T_ + c + 1)*D_ + koff)*2; }
      }
    }
  }

  f32x16 acc0, acc1;
#pragma unroll
  for (int r = 0; r < 16; ++r){ acc0[r] = 0.f; acc1[r] = 0.f; }

  float4 rg[6];
  const float4 z4 = make_float4(0.f,0.f,0.f,0.f);
#pragma unroll
  for (int s = 0; s < 6; ++s) rg[s] = fval[s] ? *reinterpret_cast<const float4*>(fptr[s]) : z4;

  for (int it = 0; it < 12; ++it){
    __syncthreads();                       // LDS consumers of prev chunk done
#pragma unroll
    for (int s = 0; s < 6; ++s){
      int f = tid + s*448;
      if (f < 2304) *reinterpret_cast<float4*>(lds + f*16) = rg[s];
    }
    __syncthreads();
    if (it < 11){                          // issue next chunk's loads early (T14)
#pragma unroll
      for (int s = 0; s < 6; ++s)
        rg[s] = fval[s] ? *reinterpret_cast<const float4*>(fptr[s] + (it+1)*128) : z4;
    }
#pragma unroll
    for (int kc = 0; kc < 4; ++kc){
      short8 av  = *reinterpret_cast<const short8*>(lds + ((w*256 + kc*64 + lane) << 4));
      short8 bv0 = *reinterpret_cast<const short8*>(lds + ((1792 + kc*64 + lane) << 4));
      short8 bv1 = *reinterpret_cast<const short8*>(lds + ((1792 + 256 + kc*64 + lane) << 4));
      acc0 = __builtin_amdgcn_mfma_f32_32x32x16_bf16(av, bv0, acc0, 0, 0, 0);
      acc1 = __builtin_amdgcn_mfma_f32_32x32x16_bf16(av, bv1, acc1, 0, 0, 0);
    }
  }

  // epilogue: scale by invnorm, per-wave argmax (C layout: col=lane&31,
  // row=(reg&3)+8*(reg>>2)+4*(lane>>5))
#pragma unroll
  for (int nt = 0; nt < 2; ++nt){
    unsigned long long key = 0ull;
#pragma unroll
    for (int r = 0; r < 16; ++r){
      int rloc = (r & 3) + 8*(r >> 2) + 4*(lane >> 5);
      int nn = w*32 + rloc;                // patch = nn+1, valid while nn<196
      float v = (nt ? acc1[r] : acc0[r]) * invn_s[nn];
      if (nn < 196){
        unsigned long long k2 = ((unsigned long long)ordf(v) << 32)
                              | (unsigned long long)(0xFFFFFFFFu - (unsigned)(nn + 1));
        if (k2 > key) key = k2;
      }
    }
    { unsigned lo = (unsigned)key, hi = (unsigned)(key >> 32);
      unsigned olo = __shfl_xor(lo, 32, 64), ohi = __shfl_xor(hi, 32, 64);
      unsigned long long o = ((unsigned long long)ohi << 32) | olo;
      if (o > key) key = o; }
    int c = nt*32 + (lane & 31);
    if (lane < 32 && c < 63) cand[w][c] = key;
  }
  __syncthreads();
  if (tid < 63){
    unsigned long long best = 0ull;
#pragma unroll
    for (int ww = 0; ww < 7; ++ww){ unsigned long long k2 = cand[ww][tid]; if (k2 > best) best = k2; }
    best_s[tid] = (int)(0xFFFFFFFFu - (unsigned)(best & 0xFFFFFFFFull));   // patch index
  }
  __syncthreads();

  // fused tok_sq from bf16 copies (L2-hot)
  float wacc = 0.f, wcnt = 0.f;
  for (int c = w; c < 63; c += 7){
    int token = c + 1;
    if (pmask[b*T_ + token] != 0) continue;
    int p = best_s[c];
    const unsigned short* tr = txt_bf + ((size_t)b*T_ + token)*D_;
    const unsigned short* gr = tgt_bf + ((size_t)b*N_ + p)*D_;
    float s = 0.f;
#pragma unroll
    for (int j = 0; j < 3; ++j){
      uint2 tv = *reinterpret_cast<const uint2*>(tr + (j*64+lane)*4);
      uint2 gv = *reinterpret_cast<const uint2*>(gr + (j*64+lane)*4);
      float d0 = bf2f(tv.x & 0xffffu) - bf2f(gv.x & 0xffffu);
      float d1 = bf2f(tv.x >> 16)     - bf2f(gv.x >> 16);
      float d2 = bf2f(tv.y & 0xffffu) - bf2f(gv.y & 0xffffu);
      float d3 = bf2f(tv.y >> 16)     - bf2f(gv.y >> 16);
      s += d0*d0 + d1*d1 + d2*d2 + d3*d3;
    }
    s = waveSum(s);
    if (lane == 0){ wacc += s; wcnt += 1.f; }
  }
  if (lane == 0){ wtok_s[w] = wacc; wkeep_s[w] = wcnt; }
  __syncthreads();
  if (tid == 0){
    float st = 0.f, sk = 0.f;
#pragma unroll
    for (int ww = 0; ww < 7; ++ww){ st += wtok_s[ww]; sk += wkeep_s[ww]; }
    tok_sum[b] = st; keep_cnt[b] = sk;
  }
}

// Kernel 3: tiny final combine
__global__ __launch_bounds__(256) void k_final2(
    const float* __restrict__ img_part, const float* __restrict__ cls_part,
    const float* __restrict__ tok_sum, const float* __restrict__ keep_cnt,
    float* __restrict__ out){
  int tid = threadIdx.x;
  float a = 0.f, c = 0.f, t = 0.f, k = 0.f;
  for (int i = tid; i < 2048; i += 256) a += img_part[i];
  for (int i = tid; i < B_; i += 256){ c += cls_part[i]; t += tok_sum[i]; k += keep_cnt[i]; }
  a = waveSum(a); c = waveSum(c); t = waveSum(t); k = waveSum(k);
  __shared__ float sh[4][4];
  int lane = tid & 63, wid = tid >> 6;
  if (lane == 0){ sh[0][wid]=a; sh[1][wid]=c; sh[2][wid]=t; sh[3][wid]=k; }
  __syncthreads();
  if (tid == 0){
    float img  = sh[0][0]+sh[0][1]+sh[0][2]+sh[0][3];
    float cls  = sh[1][0]+sh[1][1]+sh[1][2]+sh[1][3];
    float tokm = sh[2][0]+sh[2][1]+sh[2][2]+sh[2][3];
    float keep = sh[3][0]+sh[3][1]+sh[3][2]+sh[3][3];
    float kd_text = (cls + tokm) / ((128.0f + keep) * (float)D_);
    float kd_img  = img / ((float)B_ * (float)N_ * (float)D_);
    out[0] = 0.5f * (kd_text + kd_img);
  }
}

// ================= FALLBACK PATH (round-1, proven) =================
__global__ __launch_bounds__(192) void k_norm_img(
    const float* __restrict__ image, const float* __restrict__ text,
    const float* __restrict__ target, float* __restrict__ invnorm,
    float* __restrict__ img_partial, float* __restrict__ cls_partial){
  int row = blockIdx.x;
  int b = row / N_;
  int n = row - b * N_;
  int i = threadIdx.x;
  const float4* tg4 = reinterpret_cast<const float4*>(target + (size_t)row * D_);
  const float4* im4 = reinterpret_cast<const float4*>(image + (size_t)row * D_);
  float4 t4 = tg4[i];
  float4 g4 = im4[i];
  float ss = t4.x*t4.x + t4.y*t4.y + t4.z*t4.z + t4.w*t4.w;
  float dx = g4.x-t4.x, dy = g4.y-t4.y, dz = g4.z-t4.z, dw = g4.w-t4.w;
  float sd = dx*dx + dy*dy + dz*dz + dw*dw;
  ss = waveSum(ss); sd = waveSum(sd);
  __shared__ float shs[3], shd[3], shc[3];
  int lane = i & 63, wid = i >> 6;
  if (lane == 0){ shs[wid] = ss; shd[wid] = sd; }
  __syncthreads();
  if (i == 0){
    invnorm[row] = 1.0f / sqrtf(shs[0]+shs[1]+shs[2]);
    img_partial[row] = shd[0]+shd[1]+shd[2];
  }
  if (n == 0){
    const float4* tx4 = reinterpret_cast<const float4*>(text + (size_t)b * T_ * D_);
    float4 c4 = tx4[i];
    float cx = c4.x-g4.x, cy = c4.y-g4.y, cz = c4.z-g4.z, cw = c4.w-g4.w;
    float sc = cx*cx + cy*cy + cz*cz + cw*cw;
    sc = waveSum(sc);
    if (lane == 0) shc[wid] = sc;
    __syncthreads();
    if (i == 0) cls_partial[b] = shc[0]+shc[1]+shc[2];
  }
}

__global__ __launch_bounds__(256) void k_sim(
    const float* __restrict__ text, const float* __restrict__ target,
    const float* __restrict__ invnorm, unsigned long long* __restrict__ best){
  int h = blockIdx.x;
  int b = blockIdx.y;
  int n0 = 1 + 49*h;
  __shared__ float As[16][64];
  __shared__ float Bs[16][52];
  int tid = threadIdx.x;
  int tx = tid & 15, ty = tid >> 4;
  int tt = tid & 63, ki = tid >> 6;
  float acc[4][4] = {{0.f,0.f,0.f,0.f},{0.f,0.f,0.f,0.f},{0.f,0.f,0.f,0.f},{0.f,0.f,0.f,0.f}};
  const float* textb = text + (size_t)b * T_ * D_;
  const float* tgtb  = target + (size_t)b * N_ * D_;
  for (int k0 = 0; k0 < D_; k0 += 16){
    float4 av = make_float4(0.f,0.f,0.f,0.f);
    if (tt < 63) av = *reinterpret_cast<const float4*>(textb + (size_t)(1+tt)*D_ + k0 + ki*4);
    As[ki*4+0][tt] = av.x; As[ki*4+1][tt] = av.y; As[ki*4+2][tt] = av.z; As[ki*4+3][tt] = av.w;
    if (tid < 196){
      int nn = tid >> 2, kj = tid & 3;
      float4 bv = *reinterpret_cast<const float4*>(tgtb + (size_t)(n0+nn)*D_ + k0 + kj*4);
      Bs[kj*4+0][nn] = bv.x; Bs[kj*4+1][nn] = bv.y; Bs[kj*4+2][nn] = bv.z; Bs[kj*4+3][nn] = bv.w;
    }
    __syncthreads();
    if (tx < 13){
#pragma unroll
      for (int k = 0; k < 16; ++k){
        float4 a4 = *reinterpret_cast<const float4*>(&As[k][ty*4]);
        float4 b4 = *reinterpret_cast<const float4*>(&Bs[k][tx*4]);
        float aa[4] = {a4.x, a4.y, a4.z, a4.w};
        float bb[4] = {b4.x, b4.y, b4.z, b4.w};
#pragma unroll
        for (int ii = 0; ii < 4; ++ii)
#pragma unroll
          for (int jj = 0; jj < 4; ++jj)
            acc[ii][jj] = fmaf(aa[ii], bb[jj], acc[ii][jj]);
      }
    }
    __syncthreads();
  }
  float inv[4];
  if (tx < 13){
#pragma unroll
    for (int jj = 0; jj < 4; ++jj){
      int nn = tx*4 + jj;
      inv[jj] = (nn < 49) ? invnorm[(size_t)b*N_ + n0 + nn] : 0.f;
    }
  }
#pragma unroll
  for (int ii = 0; ii < 4; ++ii){
    unsigned long long key = 0ull;
    if (tx < 13){
      float bv = 0.f; int bn = -1;
#pragma unroll
      for (int jj = 0; jj < 4; ++jj){
        int nn = tx*4 + jj;
        if (nn < 49){
          float v = acc[ii][jj] * inv[jj];
          if (bn < 0 || v > bv){ bv = v; bn = n0 + nn; }
        }
      }
      if (bn >= 0)
        key = ((unsigned long long)ordf(bv) << 32) | (unsigned long long)(0xFFFFFFFFu - (unsigned)bn);
    }
#pragma unroll
    for (int m = 1; m < 16; m <<= 1){
      unsigned lo = (unsigned)key, hi = (unsigned)(key >> 32);
      unsigned olo = __shfl_xor(lo, m, 64);
      unsigned ohi = __shfl_xor(hi, m, 64);
      unsigned long long o = ((unsigned long long)ohi << 32) | olo;
      if (o > key) key = o;
    }
    int t_local = ty*4 + ii;
    if (tx == 0 && t_local < 63)
      atomicMax(&best[(size_t)b*63 + t_local], key);
  }
}

__global__ __launch_bounds__(192) void k_tok(
    const float* __restrict__ text, const float* __restrict__ target,
    const int* __restrict__ pmask, const unsigned long long* __restrict__ best,
    float* __restrict__ tok){
  int bt = blockIdx.x;
  int b = bt / 63, t = bt - b*63;
  if (pmask[b*T_ + 1 + t] != 0){
    if (threadIdx.x == 0) tok[bt] = 0.f;
    return;
  }
  unsigned long long key = best[bt];
  int n = (int)(0xFFFFFFFFu - (unsigned)(key & 0xFFFFFFFFull));
  int i = threadIdx.x;
  const float4* tx4 = reinterpret_cast<const float4*>(text + ((size_t)b*T_ + 1 + t) * D_);
  const float4* tg4 = reinterpret_cast<const float4*>(target + ((size_t)b*N_ + n) * D_);
  float4 a = tx4[i], c = tg4[i];
  float dx = a.x-c.x, dy = a.y-c.y, dz = a.z-c.z, dw = a.w-c.w;
  float sd = dx*dx + dy*dy + dz*dz + dw*dw;
  sd = waveSum(sd);
  __shared__ float sh[3];
  int lane = i & 63, wid = i >> 6;
  if (lane == 0) sh[wid] = sd;
  __syncthreads();
  if (i == 0) tok[bt] = sh[0] + sh[1] + sh[2];
}

__global__ __launch_bounds__(256) void k_final(
    const float* __restrict__ img_partial, const float* __restrict__ cls_partial,
    const float* __restrict__ tok, const int* __restrict__ pmask,
    float* __restrict__ out){
  int tid = threadIdx.x;
  float s_img = 0.f, s_cls = 0.f, s_tok = 0.f, s_keep = 0.f;
  for (int i = tid; i < B_*N_; i += 256) s_img += img_partial[i];
  for (int i = tid; i < B_;    i += 256) s_cls += cls_partial[i];
  for (int i = tid; i < B_*63; i += 256){
    s_tok += tok[i];
    int b = i / 63, t = i - b*63;
    s_keep += (pmask[b*T_ + 1 + t] == 0) ? 1.f : 0.f;
  }
  s_img = waveSum(s_img); s_cls = waveSum(s_cls);
  s_tok = waveSum(s_tok); s_keep = waveSum(s_keep);
  __shared__ float sh[4][4];
  int lane = tid & 63, wid = tid >> 6;
  if (lane == 0){ sh[0][wid]=s_img; sh[1][wid]=s_cls; sh[2][wid]=s_tok; sh[3][wid]=s_keep; }
  __syncthreads();
  if (tid == 0){
    float img  = sh[0][0]+sh[0][1]+sh[0][2]+sh[0][3];
    float cls  = sh[1][0]+sh[1][1]+sh[1][2]+sh[1][3];
    float tokm = sh[2][0]+sh[2][1]+sh[2][2]+sh[2][3];
    float keep = sh[3][0]+sh[3][1]+sh[3][2]+sh[3][3];
    float kd_text = (cls + tokm) / ((128.0f + keep) * (float)D_);
    float kd_img  = img / ((float)B_ * (float)N_ * (float)D_);
    out[0] = 0.5f * (kd_text + kd_img);
  }
}

extern "C" void kernel_launch(void* const* d_in, const int* in_sizes, int n_in,
                              void* d_out, int out_size, void* d_ws, size_t ws_size,
                              hipStream_t stream) {
  const float* image  = (const float*)d_in[0];
  const float* text   = (const float*)d_in[1];
  const float* target = (const float*)d_in[2];
  const int*   pmask  = (const int*)d_in[3];
  char* ws = (char*)d_ws;

  // new-path ws layout
  const size_t OFF_INV  = 0;                       // 25216 f32
  const size_t OFF_TGT  = 100864;                  // 128*197*768 bf16
  const size_t OFF_TXT  = 38808064;                // 128*64*768 bf16
  const size_t OFF_IMG  = 51390976;                // 2048 f32
  const size_t OFF_CLS  = 51399168;                // 128 f32
  const size_t OFF_TOK  = 51399680;                // 128 f32
  const size_t OFF_KEEP = 51400192;                // 128 f32
  const size_t NEEDED   = 51400704;

  if (ws_size >= NEEDED){
    float* invnorm = (float*)(ws + OFF_INV);
    unsigned short* tgt_bf = (unsigned short*)(ws + OFF_TGT);
    unsigned short* txt_bf = (unsigned short*)(ws + OFF_TXT);
    float* img_part = (float*)(ws + OFF_IMG);
    float* cls_part = (float*)(ws + OFF_CLS);
    float* tok_sum  = (float*)(ws + OFF_TOK);
    float* keep_cnt = (float*)(ws + OFF_KEEP);

    k_prep<<<2048, 256, 0, stream>>>(image, text, target, invnorm, tgt_bf, txt_bf,
                                     img_part, cls_part);
    k_sim2<<<B_, 448, 0, stream>>>(txt_bf, tgt_bf, invnorm, pmask, tok_sum, keep_cnt);
    k_final2<<<1, 256, 0, stream>>>(img_part, cls_part, tok_sum, keep_cnt, (float*)d_out);
  } else {
    float* invnorm           = (float*)(ws);
    unsigned long long* best = (unsigned long long*)(ws + 100864);
    float* img_partial       = (float*)(ws + 165376);
    float* cls_partial       = (float*)(ws + 266240);
    float* tok               = (float*)(ws + 266752);
    hipMemsetAsync(ws + 100864, 0, 64512, stream);
    k_norm_img<<<B_*N_, 192, 0, stream>>>(image, text, target, invnorm, img_partial, cls_partial);
    k_sim<<<dim3(4, B_), 256, 0, stream>>>(text, target, invnorm, best);
    k_tok<<<B_*63, 192, 0, stream>>>(text, target, pmask, best, tok);
    k_final<<<1, 256, 0, stream>>>(img_partial, cls_partial, tok, pmask, (float*)d_out);
  }
}